// Round 12
// baseline (121.252 us; speedup 1.0000x reference)
//
#include <hip/hip_runtime.h>
#include <hip/hip_bf16.h>
#include <math.h>

// Dtype model (pinned R0-R4): float inputs f32; edge_index int32; d_out read
// as f32: chunk0 = pred f32[0:393216], chunk1 = yg f32[393216:786432]; np
// reference computed from bf16-cast inputs -> bf16 intermediates safe.
//
// R7: register spills kill. R9: strided us8 LDS reads = bank conflicts.
// R10: P[64x64]@X MFMA aggregation + transposed xs + prepacked W^T.
// R11: both GAT layers fused per-graph @512thr -> 118.6us; gat <41us bound,
//      latency/barrier-bound at 1 block/CU (grid=256 graphs, no 2nd block).
// R12 (this): gat @1024 threads (16 waves = 4/SIMD, 2x latency overlap),
//      GEMM split (chunk x row-half)/wave, agg split across all 16 waves;
//      fw1/fw2 prepacked bf16-transposed so mlp staging is pure us8 copies.

#define N_NODES 16384
#define B_GRAPHS 256
#define K_NODES 64
#define DEG 8
#define NHEADS 4
#define C1 100
#define C2 128
#define IN_F 96
#define HID 64
#define OUT_SZ 24
#define PRED_ELEMS (K_NODES * B_GRAPHS * OUT_SZ)   // 393216

#define W1T_ROWS 448   // 400 cols padded to 7*64
#define W1T_K    96
#define W2T_ROWS 512
#define W2T_K    128   // 100 padded

using bf16 = __hip_bfloat16;
typedef __attribute__((ext_vector_type(8))) short          frag_ab;  // 8 bf16
typedef __attribute__((ext_vector_type(4))) float          frag_cd;  // 4 f32
typedef unsigned short us8 __attribute__((ext_vector_type(8)));      // 16 B
typedef unsigned short us4 __attribute__((ext_vector_type(4)));      // 8 B

__device__ __forceinline__ float us2f(unsigned short u) {
  return __bfloat162float(__ushort_as_bfloat16(u));
}
__device__ __forceinline__ short f2bf_s(float f) {
  return __builtin_bit_cast(short, __float2bfloat16(f));
}

// ---------------------------------------------------------------------------
// prep: pack W1^T/W2^T + fw1^T/fw2^T (bf16, padded, layouts the consumers
// stage with us8 copies) + yg = float(bf16(y)). One launch, all independent.
// ---------------------------------------------------------------------------
#define P1N (W1T_ROWS * W1T_K)        // 43008
#define P2N (W2T_ROWS * W2T_K)        // 65536
#define F1N (K_NODES * HID * C2)      // 524288 : fw1t[k][j*128+i]
#define F2N (K_NODES * 32 * HID)      // 131072 : fw2t[k][q*64+j], q padded 32
#define YG4 (PRED_ELEMS / 4)          // 98304
#define PREPN (P1N + P2N + F1N + F2N + YG4)   // 862208 = 3368*256

__global__ __launch_bounds__(256)
void prep(const float* __restrict__ W1, const float* __restrict__ W2,
          const float* __restrict__ fw1, const float* __restrict__ fw2,
          const float* __restrict__ y,
          bf16* __restrict__ W1t, bf16* __restrict__ W2t,
          bf16* __restrict__ fw1t, bf16* __restrict__ fw2t,
          float* __restrict__ yg) {
  int idx = blockIdx.x * 256 + threadIdx.x;
  if (idx < P1N) {
    int c = idx / W1T_K, k = idx - c * W1T_K;
    W1t[idx] = __float2bfloat16((c < 400) ? W1[(size_t)k * 400 + c] : 0.f);
  } else if (idx < P1N + P2N) {
    int i2 = idx - P1N;
    int c = i2 >> 7, k = i2 & 127;
    W2t[i2] = __float2bfloat16((k < 100) ? W2[(size_t)k * 512 + c] : 0.f);
  } else if (idx < P1N + P2N + F1N) {
    int i2 = idx - P1N - P2N;
    int k = i2 >> 13, r = i2 & 8191, j = r >> 7, i = r & 127;
    fw1t[i2] = __float2bfloat16(fw1[(size_t)k * 8192 + i * 64 + j]);
  } else if (idx < P1N + P2N + F1N + F2N) {
    int i2 = idx - P1N - P2N - F1N;
    int k = i2 >> 11, r = i2 & 2047, q = r >> 6, j = r & 63;
    fw2t[i2] = __float2bfloat16((q < OUT_SZ) ? fw2[(size_t)k * 1536 + j * 24 + q] : 0.f);
  } else {
    int j = idx - P1N - P2N - F1N - F2N;
    if (j < YG4) {
      int i = j * 4;
      float4 v = *(const float4*)(y + i);
      v.x = __bfloat162float(__float2bfloat16(v.x));
      v.y = __bfloat162float(__float2bfloat16(v.y));
      v.z = __bfloat162float(__float2bfloat16(v.z));
      v.w = __bfloat162float(__float2bfloat16(v.w));
      *(float4*)(yg + i) = v;
    }
  }
}

// ---------------------------------------------------------------------------
// Fused two-layer GAT, one block per graph (grid=256), 1024 threads (16 waves
// = 4 waves/SIMD for latency overlap at 1 block/CU).
// ---------------------------------------------------------------------------
__global__ __launch_bounds__(1024)
void gat_fused(const float* __restrict__ x,
               const bf16* __restrict__ W1t, const bf16* __restrict__ W2t,
               const int* __restrict__ esrc,
               const float* __restrict__ as1, const float* __restrict__ ad1,
               const float* __restrict__ b1,
               const float* __restrict__ as2, const float* __restrict__ ad2,
               const float* __restrict__ b2,
               bf16* __restrict__ h2out) {
  constexpr int LDA1 = IN_F + 8;     // 104 shorts
  constexpr int LDA2 = 136;          // layer-2 A stride (128 + 8)
  constexpr int LDT  = 72;           // xs/Ps row stride

  __shared__ __align__(16) short          As[64 * LDA2];          // 17.4 KB
  __shared__ __align__(16) unsigned short xs[512 * LDT];          // 73.7 KB
  __shared__ __align__(16) short          Ps[NHEADS * 64 * LDT];  // 36.9 KB
  __shared__ float avs1[400], avd1[400], avs2[512], avd2[512];
  __shared__ float bia1[C1], bia2[C2];
  __shared__ int   edg[K_NODES * DEG];
  __shared__ float als[64 * 5], ald[64 * 5];

  const int g = blockIdx.x;
  const int t = threadIdx.x;
  const int wv = t >> 6;
  const int l  = t & 63;
  const int lm = l & 15;
  const int lk = (l >> 4) * 8;
  const int rq = (l >> 4) * 4;

  // ================= phase 0: stage =================
  {
    constexpr int QR = IN_F / 4;     // 24 float4 per row
    for (int idx = t; idx < 64 * QR; idx += 1024) {
      int m = idx / QR, q = idx - m * QR;
      const float4 v = *(const float4*)(x + ((size_t)(g * 64 + m) * IN_F + q * 4));
      short* d = &As[m * LDA1 + q * 4];
      d[0] = f2bf_s(v.x); d[1] = f2bf_s(v.y); d[2] = f2bf_s(v.z); d[3] = f2bf_s(v.w);
    }
  }
  if (t < 400)        { avs1[t] = as1[t]; avd1[t] = ad1[t]; }
  else if (t < 912)   { int i = t - 400; avs2[i] = as2[i]; avd2[i] = ad2[i]; }
  if (t >= 912 && t < 912 + C1) bia1[t - 912] = b1[t - 912];
  if (t < C2) bia2[t] = b2[t];   // overlaps other work groups harmlessly
  if (t >= 512 && t < 512 + K_NODES * DEG)
    edg[t - 512] = esrc[g * K_NODES * DEG + (t - 512)] & (K_NODES - 1);
  for (int idx = t; idx < NHEADS * 64 * LDT / 8; idx += 1024)
    *(us8*)&Ps[idx * 8] = (us8)0;
  __syncthreads();

  // ========== L1 GEMM: xl1 = As @ W1t -> xs^T. wave = (chunk, row-half) ======
  if (wv < 14) {
    const int ch = wv >> 1;
    const int mh = (wv & 1) * 32;
    const int n0 = ch * 64;
    frag_cd acc[2][4] = {};
#pragma unroll
    for (int ks = 0; ks < IN_F; ks += 32) {
      frag_ab b[4];
#pragma unroll
      for (int nt = 0; nt < 4; ++nt)
        b[nt] = *(const frag_ab*)((const short*)W1t +
                                  (size_t)(n0 + nt * 16 + lm) * W1T_K + ks + lk);
#pragma unroll
      for (int mt = 0; mt < 2; ++mt) {
        frag_ab a = *(const frag_ab*)&As[(mh + mt * 16 + lm) * LDA1 + ks + lk];
#pragma unroll
        for (int nt = 0; nt < 4; ++nt)
          acc[mt][nt] = __builtin_amdgcn_mfma_f32_16x16x32_bf16(a, b[nt],
                                                                acc[mt][nt], 0, 0, 0);
      }
    }
#pragma unroll
    for (int mt = 0; mt < 2; ++mt)
#pragma unroll
      for (int nt = 0; nt < 4; ++nt) {
        const int c4 = n0 + nt * 16 + lm;
        us4 o;
#pragma unroll
        for (int r = 0; r < 4; ++r) o[r] = (unsigned short)f2bf_s(acc[mt][nt][r]);
        *(us4*)&xs[c4 * LDT + mh + mt * 16 + rq] = o;
      }
  }
  __syncthreads();

  // ================= L1 logits (waves 0-3) =================
  if (t < 256) {
    const int n = t >> 2, h = t & 3;
    float ss = 0.f, sd = 0.f;
#pragma unroll 4
    for (int c = 0; c < C1; ++c) {
      const float v = us2f(xs[(h * C1 + c) * LDT + n]);
      ss += v * avs1[h * C1 + c];
      sd += v * avd1[h * C1 + c];
    }
    als[n * 5 + h] = ss;
    ald[n * 5 + h] = sd;
  }
  __syncthreads();

  // ====== L1 softmax -> Ps (waves 0-3); spare waves zero As2 k-pads ======
  if (t < 256) {
    const int n = t >> 2, h = t & 3;
    const float ad = ald[n * 5 + h];
    int   sv[9];
    float a[9];
#pragma unroll
    for (int j = 0; j < 8; ++j) sv[j] = edg[n * DEG + j];
    sv[8] = n;
#pragma unroll
    for (int j = 0; j < 9; ++j) {
      float v = als[sv[j] * 5 + h] + ad;
      a[j] = (v >= 0.f) ? v : 0.2f * v;       // leaky_relu 0.2
    }
    float m = -1e30f;
#pragma unroll
    for (int j = 0; j < 9; ++j) m = fmaxf(m, a[j]);
    float s = 0.f;
#pragma unroll
    for (int j = 0; j < 9; ++j) { a[j] = __expf(a[j] - m); s += a[j]; }
    const float inv = 1.f / (s + 1e-16f);
    short* prow = &Ps[(h * 64 + n) * LDT];
#pragma unroll
    for (int j = 0; j < 9; ++j) {
      float tw = a[j];
#pragma unroll
      for (int i = 0; i < 9; ++i)
        if (i != j && sv[i] == sv[j]) tw += a[i];
      prow[sv[j]] = f2bf_s(tw * inv);         // idempotent dedupe
    }
  } else {
    // zero As layer-2 k-padding (k = 100..127); As1 content is dead here
    for (int i = t - 256; i < 64 * 28; i += 768) {
      int m = i / 28, kk = 100 + (i - m * 28);
      As[m * LDA2 + kk] = 0;
    }
  }
  __syncthreads();

  // ====== L1 agg: h1 = 0.25*sum_h P_h @ X_h + bias, ELU -> As2.
  //        wave = (row-quarter mw, tile-pair ntg); NT=7 tiles ======
  {
    const int mw  = (wv & 3) * 16;
    const int ntg = wv >> 2;                  // 0..3 -> tiles {2g, 2g+1} cap 7
    frag_cd acc[2] = {};
#pragma unroll
    for (int h = 0; h < NHEADS; ++h)
#pragma unroll
      for (int ks = 0; ks < 64; ks += 32) {
        frag_ab a = *(const frag_ab*)&Ps[(h * 64 + mw + lm) * LDT + ks + lk];
#pragma unroll
        for (int u = 0; u < 2; ++u) {
          const int nt = ntg * 2 + u;
          if (nt < 7) {
            frag_ab b = *(const frag_ab*)&xs[(h * C1 + nt * 16 + lm) * LDT + ks + lk];
            acc[u] = __builtin_amdgcn_mfma_f32_16x16x32_bf16(a, b, acc[u], 0, 0, 0);
          }
        }
      }
#pragma unroll
    for (int u = 0; u < 2; ++u) {
      const int nt = ntg * 2 + u;
      if (nt < 7) {
        const int c = nt * 16 + lm;
        if (c < C1) {
          const float bc = bia1[c];
#pragma unroll
          for (int r = 0; r < 4; ++r) {
            float vv = acc[u][r] * 0.25f + bc;
            vv = (vv > 0.f) ? vv : (__expf(vv) - 1.f);   // ELU
            As[(mw + rq + r) * LDA2 + c] = f2bf_s(vv);
          }
        }
      }
    }
  }
  __syncthreads();

  // ========== L2 GEMM: xl2 = As @ W2t -> xs^T. wave = (chunk, row-half) ======
  {
    const int ch = wv >> 1;                  // 0..7
    const int mh = (wv & 1) * 32;
    const int n0 = ch * 64;
    frag_cd acc[2][4] = {};
#pragma unroll
    for (int ks = 0; ks < 128; ks += 32) {
      frag_ab b[4];
#pragma unroll
      for (int nt = 0; nt < 4; ++nt)
        b[nt] = *(const frag_ab*)((const short*)W2t +
                                  (size_t)(n0 + nt * 16 + lm) * W2T_K + ks + lk);
#pragma unroll
      for (int mt = 0; mt < 2; ++mt) {
        frag_ab a = *(const frag_ab*)&As[(mh + mt * 16 + lm) * LDA2 + ks + lk];
#pragma unroll
        for (int nt = 0; nt < 4; ++nt)
          acc[mt][nt] = __builtin_amdgcn_mfma_f32_16x16x32_bf16(a, b[nt],
                                                                acc[mt][nt], 0, 0, 0);
      }
    }
#pragma unroll
    for (int mt = 0; mt < 2; ++mt)
#pragma unroll
      for (int nt = 0; nt < 4; ++nt) {
        const int c4 = n0 + nt * 16 + lm;
        us4 o;
#pragma unroll
        for (int r = 0; r < 4; ++r) o[r] = (unsigned short)f2bf_s(acc[mt][nt][r]);
        *(us4*)&xs[c4 * LDT + mh + mt * 16 + rq] = o;
      }
  }
  __syncthreads();

  // ================= L2 logits (waves 0-3) =================
  if (t < 256) {
    const int n = t >> 2, h = t & 3;
    float ss = 0.f, sd = 0.f;
#pragma unroll 4
    for (int c = 0; c < C2; ++c) {
      const float v = us2f(xs[(h * C2 + c) * LDT + n]);
      ss += v * avs2[h * C2 + c];
      sd += v * avd2[h * C2 + c];
    }
    als[n * 5 + h] = ss;
    ald[n * 5 + h] = sd;
  }
  __syncthreads();

  // ====== L2 softmax -> Ps (same nonzero support; no re-zero) ======
  if (t < 256) {
    const int n = t >> 2, h = t & 3;
    const float ad = ald[n * 5 + h];
    int   sv[9];
    float a[9];
#pragma unroll
    for (int j = 0; j < 8; ++j) sv[j] = edg[n * DEG + j];
    sv[8] = n;
#pragma unroll
    for (int j = 0; j < 9; ++j) {
      float v = als[sv[j] * 5 + h] + ad;
      a[j] = (v >= 0.f) ? v : 0.2f * v;
    }
    float m = -1e30f;
#pragma unroll
    for (int j = 0; j < 9; ++j) m = fmaxf(m, a[j]);
    float s = 0.f;
#pragma unroll
    for (int j = 0; j < 9; ++j) { a[j] = __expf(a[j] - m); s += a[j]; }
    const float inv = 1.f / (s + 1e-16f);
    short* prow = &Ps[(h * 64 + n) * LDT];
#pragma unroll
    for (int j = 0; j < 9; ++j) {
      float tw = a[j];
#pragma unroll
      for (int i = 0; i < 9; ++i)
        if (i != j && sv[i] == sv[j]) tw += a[i];
      prow[sv[j]] = f2bf_s(tw * inv);
    }
  }
  __syncthreads();

  // ====== L2 agg: h2 = 0.25*sum_h P_h @ X_h + bias -> global. NT=8 ======
  {
    const int mw  = (wv & 3) * 16;
    const int ntg = wv >> 2;                  // tiles {2g, 2g+1}
    frag_cd acc[2] = {};
#pragma unroll
    for (int h = 0; h < NHEADS; ++h)
#pragma unroll
      for (int ks = 0; ks < 64; ks += 32) {
        frag_ab a = *(const frag_ab*)&Ps[(h * 64 + mw + lm) * LDT + ks + lk];
#pragma unroll
        for (int u = 0; u < 2; ++u) {
          frag_ab b = *(const frag_ab*)&xs[(h * C2 + (ntg * 2 + u) * 16 + lm) * LDT + ks + lk];
          acc[u] = __builtin_amdgcn_mfma_f32_16x16x32_bf16(a, b, acc[u], 0, 0, 0);
        }
      }
    unsigned short* outp = (unsigned short*)h2out + (size_t)(g * 64) * C2;
#pragma unroll
    for (int u = 0; u < 2; ++u) {
      const int c = (ntg * 2 + u) * 16 + lm;
      const float bc = bia2[c];
#pragma unroll
      for (int r = 0; r < 4; ++r) {
        float vv = acc[u][r] * 0.25f + bc;
        outp[(size_t)(mw + rq + r) * C2 + c] = (unsigned short)f2bf_s(vv);
      }
    }
  }
}

// ---------------------------------------------------------------------------
// MFMA MLP head (verified R8/R10). Grid 256 = (k) x (ms). B1/B2 staged from
// prepacked bf16 via us8 copies.
// ---------------------------------------------------------------------------
__global__ __launch_bounds__(256)
void mlp_mfma(const bf16* __restrict__ h2,
              const bf16* __restrict__ fw1t, const float* __restrict__ fb1,
              const bf16* __restrict__ fw2t, const float* __restrict__ fb2,
              float* __restrict__ pred) {
  constexpr int LDA = C2 + 8;
  constexpr int LDH = HID + 8;
  __shared__ __align__(16) short As[64 * LDA];
  __shared__ __align__(16) short B1[HID * LDA];
  __shared__ __align__(16) short Hs[64 * LDH];
  __shared__ __align__(16) short B2[32 * LDH];
  __shared__ float b1s[HID];
  __shared__ float b2s[32];

  const int k  = blockIdx.x & 63;
  const int ms = blockIdx.x >> 6;
  const int t  = threadIdx.x;

  for (int idx = t; idx < 64 * 16; idx += 256) {
    int r = idx >> 4, o = idx & 15;
    const us8 v = *(const us8*)((const unsigned short*)h2 +
        ((size_t)((ms * 64 + r) * K_NODES + k) * C2) + o * 8);
    *(us8*)&As[r * LDA + o * 8] = v;
  }
  for (int idx = t; idx < HID * 16; idx += 256) {      // 1024 us8 chunks
    int n = idx >> 4, o = idx & 15;
    *(us8*)&B1[n * LDA + o * 8] =
        *(const us8*)((const unsigned short*)fw1t + (size_t)k * 8192 + n * 128 + o * 8);
  }
  for (int idx = t; idx < 32 * 8; idx += 256) {        // 256 us8 chunks
    int q = idx >> 3, o = idx & 7;
    *(us8*)&B2[q * LDH + o * 8] =
        *(const us8*)((const unsigned short*)fw2t + (size_t)k * 2048 + q * 64 + o * 8);
  }
  if (t < HID) b1s[t] = fb1[k * HID + t];
  if (t < 32)  b2s[t] = (t < OUT_SZ) ? fb2[k * OUT_SZ + t] : 0.f;
  __syncthreads();

  const int wv = t >> 6;
  const int l  = t & 63;
  const int lm = l & 15;
  const int lk = (l >> 4) * 8;
  const int rq = (l >> 4) * 4;

  frag_cd acc[4] = {};
#pragma unroll
  for (int ks = 0; ks < C2; ks += 32) {
    frag_ab a = *(const frag_ab*)&As[(wv * 16 + lm) * LDA + ks + lk];
#pragma unroll
    for (int nt = 0; nt < 4; ++nt) {
      frag_ab b = *(const frag_ab*)&B1[(nt * 16 + lm) * LDA + ks + lk];
      acc[nt] = __builtin_amdgcn_mfma_f32_16x16x32_bf16(a, b, acc[nt], 0, 0, 0);
    }
  }
#pragma unroll
  for (int nt = 0; nt < 4; ++nt) {
    const int j  = nt * 16 + lm;
    const float bj = b1s[j];
#pragma unroll
    for (int r = 0; r < 4; ++r) {
      const int m = wv * 16 + rq + r;
      Hs[m * LDH + j] = f2bf_s(fmaxf(acc[nt][r] + bj, 0.f));
    }
  }
  __syncthreads();

  frag_cd acc2[2] = {};
#pragma unroll
  for (int ks = 0; ks < HID; ks += 32) {
    frag_ab a = *(const frag_ab*)&Hs[(wv * 16 + lm) * LDH + ks + lk];
#pragma unroll
    for (int nt = 0; nt < 2; ++nt) {
      frag_ab b = *(const frag_ab*)&B2[(nt * 16 + lm) * LDH + ks + lk];
      acc2[nt] = __builtin_amdgcn_mfma_f32_16x16x32_bf16(a, b, acc2[nt], 0, 0, 0);
    }
  }
#pragma unroll
  for (int nt = 0; nt < 2; ++nt) {
    const int q = nt * 16 + lm;
    if (q < OUT_SZ) {
      const float bq = b2s[q];
#pragma unroll
      for (int r = 0; r < 4; ++r) {
        const int m = wv * 16 + rq + r;
        pred[((size_t)k * B_GRAPHS + ms * 64 + m) * OUT_SZ + q] = acc2[nt][r] + bq;
      }
    }
  }
}

// ---------------------------------------------------------------------------
extern "C" void kernel_launch(void* const* d_in, const int* in_sizes, int n_in,
                              void* d_out, int out_size, void* d_ws, size_t ws_size,
                              hipStream_t stream) {
  const float* x   = (const float*)d_in[0];
  const int*   ei  = (const int*)d_in[1];    // [2,E]: first E entries = src
  const float* y   = (const float*)d_in[3];
  const float* W1  = (const float*)d_in[4];
  const float* as1 = (const float*)d_in[5];
  const float* ad1 = (const float*)d_in[6];
  const float* b1  = (const float*)d_in[7];
  const float* W2  = (const float*)d_in[8];
  const float* as2 = (const float*)d_in[9];
  const float* ad2 = (const float*)d_in[10];
  const float* b2  = (const float*)d_in[11];
  const float* fw1 = (const float*)d_in[12];
  const float* fb1 = (const float*)d_in[13];
  const float* fw2 = (const float*)d_in[14];
  const float* fb2 = (const float*)d_in[15];

  // Workspace (~5.7 MB): h2, W1t, W2t, fw1t, fw2t
  bf16* h2   = (bf16*)d_ws;
  bf16* W1t  = h2 + (size_t)N_NODES * C2;
  bf16* W2t  = W1t + P1N;
  bf16* fw1t = W2t + P2N;
  bf16* fw2t = fw1t + F1N;

  float* out = (float*)d_out;

  // ---- prep: pack weights + yg ----
  prep<<<PREPN / 256, 256, 0, stream>>>(W1, W2, fw1, fw2, y,
                                        W1t, W2t, fw1t, fw2t, out + PRED_ELEMS);

  // ---- fused two-layer GAT -> h2 ----
  gat_fused<<<B_GRAPHS, 1024, 0, stream>>>(x, W1t, W2t, ei,
                                           as1, ad1, b1, as2, ad2, b2, h2);

  // ---- MFMA MLP head -> pred (chunk0, f32) ----
  mlp_mfma<<<K_NODES * 4, 256, 0, stream>>>(h2, fw1t, fb1, fw2t, fb2, out);
}